// Round 2
// baseline (7310.940 us; speedup 1.0000x reference)
//
#include <hip/hip_runtime.h>
#include <hip/hip_bf16.h>

#define R_TOTAL 36864            // 2 sides * BS(2) * 9216 rows
#define NE      4718592          // R_TOTAL*128
#define HALF_E  2359296          // per-side feature elements (18432*128)
#define ATTN_E  3538944          // 2*48*192*192
#define SEQ     9216             // rows per linear-attn batch (4 batches)
#define NCHUNK  9                // linear-attn reduction chunks (9216/9=1024)

// ---------------- elementwise helpers ----------------
__global__ void k_copy(const float* __restrict__ in, float* __restrict__ out, int n) {
  for (int i = blockIdx.x*blockDim.x + threadIdx.x; i < n; i += gridDim.x*blockDim.x)
    out[i] = in[i];
}
__global__ void k_zero(float* __restrict__ p, int n) {
  for (int i = blockIdx.x*blockDim.x + threadIdx.x; i < n; i += gridDim.x*blockDim.x)
    p[i] = 0.f;
}
__global__ void k_addf(const float* __restrict__ base, const float* __restrict__ acc,
                       float* __restrict__ out, int n) {
  for (int i = blockIdx.x*blockDim.x + threadIdx.x; i < n; i += gridDim.x*blockDim.x)
    out[i] = base[i] + acc[i];
}

// ---------------- LayerNorm: 4 rows/block, one row per wave ----------------
__global__ __launch_bounds__(256) void k_ln(const float* __restrict__ X,
                                            const float* __restrict__ g,
                                            const float* __restrict__ b,
                                            float* __restrict__ Y) {
  int wave = threadIdx.x >> 6, lane = threadIdx.x & 63;
  int row = blockIdx.x*4 + wave;
  const float* x = X + (size_t)row*128 + lane*2;
  float x0 = x[0], x1 = x[1];
  float s = x0 + x1, sq = x0*x0 + x1*x1;
  #pragma unroll
  for (int o = 32; o >= 1; o >>= 1) { s += __shfl_xor(s, o, 64); sq += __shfl_xor(sq, o, 64); }
  float mean = s * (1.f/128.f);
  float var  = sq * (1.f/128.f) - mean*mean;
  float inv  = rsqrtf(var + 1e-5f);
  float g0 = g[lane*2], b0 = b[lane*2];
  float g1 = g[lane*2+1], b1 = b[lane*2+1];
  float* y = Y + (size_t)row*128 + lane*2;
  y[0] = (x0-mean)*inv*g0 + b0;
  y[1] = (x1-mean)*inv*g1 + b1;
}

// ---------------- GEMM: C[M,128] = epi(A[M,128] @ W[128,128]^T [+R]) ----------------
// EPI: 0 = none, 1 = +R residual, 2 = exact gelu, 3 = elu+1 (phi)
template<int EPI>
__global__ __launch_bounds__(256) void k_gemm(const float* __restrict__ A,
                                              const float* __restrict__ W,
                                              const float* __restrict__ R,
                                              float* __restrict__ C) {
  __shared__ float As[64][33];
  __shared__ float Ws[128][33];
  int tid = threadIdx.x;
  int row0 = blockIdx.x * 64;
  int tm = tid >> 5, tn = tid & 31;
  float acc[8][4] = {};
  for (int k0 = 0; k0 < 128; k0 += 32) {
    __syncthreads();
    for (int i = tid; i < 64*32; i += 256) {
      int r = i >> 5, kk = i & 31;
      As[r][kk] = A[(size_t)(row0 + r)*128 + k0 + kk];
    }
    for (int i = tid; i < 128*32; i += 256) {
      int c = i >> 5, kk = i & 31;
      Ws[c][kk] = W[(size_t)c*128 + k0 + kk];
    }
    __syncthreads();
    #pragma unroll
    for (int kk = 0; kk < 32; kk++) {
      float a[8], w[4];
      #pragma unroll
      for (int i = 0; i < 8; i++) a[i] = As[tm*8 + i][kk];
      #pragma unroll
      for (int j = 0; j < 4; j++) w[j] = Ws[tn + 32*j][kk];
      #pragma unroll
      for (int i = 0; i < 8; i++)
        #pragma unroll
        for (int j = 0; j < 4; j++)
          acc[i][j] += a[i]*w[j];
    }
  }
  #pragma unroll
  for (int i = 0; i < 8; i++) {
    int r = row0 + tm*8 + i;
    #pragma unroll
    for (int j = 0; j < 4; j++) {
      int c = tn + 32*j;
      float v = acc[i][j];
      if (EPI == 1) v += R[(size_t)r*128 + c];
      if (EPI == 2) v = 0.5f*v*(1.0f + erff(v*0.70710678118f));
      if (EPI == 3) v = (v > 0.f) ? v + 1.0f : __expf(v);
      C[(size_t)r*128 + c] = v;
    }
  }
}

// ---------------- linear attention: KV/Ksum partial reduce ----------------
// grid (32 = n*8+h, NCHUNK). Deterministic: each block writes its own 272-slot.
__global__ __launch_bounds__(256) void k_linred(const float* __restrict__ K,
                                                const float* __restrict__ V,
                                                float* __restrict__ kvp) {
  int nh = blockIdx.x;
  int n = nh >> 3, h = nh & 7;
  int chunk = blockIdx.y;
  int r0 = chunk * (SEQ / NCHUNK);
  const float* kb = K + (size_t)n*SEQ*128 + h*16;
  const float* vb = V + (size_t)n*SEQ*128 + h*16;
  __shared__ float ks[16][17], vs[16][17];
  int tid = threadIdx.x;
  int d1 = tid >> 4, d2 = tid & 15;
  float kv = 0.f, ksum = 0.f;
  for (int r = r0; r < r0 + SEQ/NCHUNK; r += 16) {
    __syncthreads();
    int rr = tid >> 4, dd = tid & 15;
    ks[rr][dd] = kb[(size_t)(r + rr)*128 + dd];
    vs[rr][dd] = vb[(size_t)(r + rr)*128 + dd];
    __syncthreads();
    #pragma unroll
    for (int j = 0; j < 16; j++) {
      float kvl = ks[j][d1];
      kv   += kvl * vs[j][d2];
      ksum += kvl;
    }
  }
  float* dst = kvp + ((size_t)nh*NCHUNK + chunk)*272;
  dst[d1*16 + d2] = kv;
  if (d2 == 0) dst[256 + d1] = ksum;
}

// ---------------- linear attention: apply ----------------
__global__ __launch_bounds__(256) void k_linapply(const float* __restrict__ Q,
                                                  const float* __restrict__ kvp,
                                                  float* __restrict__ MSG) {
  __shared__ float kv[8*272];
  int row0 = blockIdx.x * 16;
  int n = row0 / SEQ;
  int tid = threadIdx.x;
  for (int i = tid; i < 8*272; i += 256) {
    int h = i / 272, j = i % 272;
    const float* src = kvp + ((size_t)(n*8 + h)*NCHUNK)*272 + j;
    float s = 0.f;
    #pragma unroll
    for (int c2 = 0; c2 < NCHUNK; c2++) s += src[(size_t)c2*272];
    kv[i] = s;
  }
  __syncthreads();
  #pragma unroll
  for (int p = 0; p < 8; p++) {
    int idx = tid + p*256;          // 2048 outputs = 16 rows * 128 cols
    int rl = idx >> 7, c = idx & 127;
    int h = c >> 4, d = c & 15;
    int row = row0 + rl;
    const float* qr = Q + (size_t)row*128 + h*16;
    float z = 1e-6f, o = 0.f;
    #pragma unroll
    for (int dd = 0; dd < 16; dd++) {
      float qv = qr[dd];
      z += qv * kv[h*272 + 256 + dd];
      o += qv * kv[h*272 + dd*16 + d];
    }
    MSG[(size_t)row*128 + c] = o / z;
  }
}

// ---------------- full attention (cross layer), raw accumulation ----------------
// grid.x = 96*48 (n, l-tile of 4), grid.y = side (0: q=left,kv=right -> msg left)
__global__ __launch_bounds__(256) void k_fullattn(const float* __restrict__ Q,
                                                  const float* __restrict__ K,
                                                  const float* __restrict__ V,
                                                  float* __restrict__ MSG,
                                                  float* __restrict__ AL,
                                                  float* __restrict__ AR) {
  int side = blockIdx.y;
  int n  = blockIdx.x / 48;
  int l0 = (blockIdx.x % 48) * 4;
  size_t qoff = side ? (size_t)HALF_E : 0;
  size_t koff = side ? 0 : (size_t)HALF_E;
  const float* q = Q + qoff + ((size_t)n*192 + l0)*128;
  const float* k = K + koff + (size_t)n*192*128;
  const float* v = V + koff + (size_t)n*192*128;
  float* raw = (side ? AR : AL) + ((size_t)n*192 + l0)*192;

  __shared__ float q4[512];        // 4 q-rows
  __shared__ float sc[32*193];     // [h*4+l][192] padded
  __shared__ float kt[32*129];     // K/V staging tile

  int tid = threadIdx.x;
  for (int i = tid; i < 512; i += 256) q4[i] = q[i];

  // phase 1: scores
  for (int s0 = 0; s0 < 192; s0 += 32) {
    __syncthreads();
    for (int i = tid; i < 4096; i += 256) {
      int r = i >> 7, c = i & 127;
      kt[r*129 + c] = k[(size_t)(s0 + r)*128 + c];
    }
    __syncthreads();
    #pragma unroll
    for (int p = 0; p < 4; p++) {
      int idx = tid + p*256;
      int sl = idx & 31, h = (idx >> 5) & 7, l = idx >> 8;
      float d = 0.f;
      #pragma unroll
      for (int dd = 0; dd < 16; dd++)
        d += q4[l*128 + h*16 + dd] * kt[sl*129 + h*16 + dd];
      sc[(h*4 + l)*193 + s0 + sl] = d * 0.25f;   // scale = 1/sqrt(16)
    }
  }
  __syncthreads();

  // phase 2: softmax over s for each (h,l); 4 waves x 8 rows
  int wave = tid >> 6, lane = tid & 63;
  for (int j = 0; j < 8; j++) {
    float* row = &sc[(wave*8 + j)*193];
    float m = fmaxf(fmaxf(row[lane], row[lane+64]), row[lane+128]);
    #pragma unroll
    for (int o = 32; o >= 1; o >>= 1) m = fmaxf(m, __shfl_xor(m, o, 64));
    float e0 = __expf(row[lane]-m), e1 = __expf(row[lane+64]-m), e2 = __expf(row[lane+128]-m);
    float s = e0 + e1 + e2;
    #pragma unroll
    for (int o = 32; o >= 1; o >>= 1) s += __shfl_xor(s, o, 64);
    float inv = 1.f / s;
    row[lane] = e0*inv; row[lane+64] = e1*inv; row[lane+128] = e2*inv;
  }
  __syncthreads();

  // phase 3: raw[l][s] += sum_h A  (single writer per location -> deterministic)
  #pragma unroll
  for (int p = 0; p < 3; p++) {
    int idx = tid + p*256;           // 768 = 4*192
    int l = idx / 192, s = idx % 192;
    float r = 0.f;
    #pragma unroll
    for (int h = 0; h < 8; h++) r += sc[(h*4 + l)*193 + s];
    raw[(size_t)l*192 + s] += r;
  }

  // phase 4: out = A @ V
  float acc0 = 0.f, acc1 = 0.f;
  for (int s0 = 0; s0 < 192; s0 += 32) {
    __syncthreads();
    for (int i = tid; i < 4096; i += 256) {
      int r = i >> 7, c = i & 127;
      kt[r*129 + c] = v[(size_t)(s0 + r)*128 + c];
    }
    __syncthreads();
    {
      int idx = tid;
      int l = idx >> 7, c = idx & 127, h = c >> 4;
      #pragma unroll
      for (int sl = 0; sl < 32; sl++)
        acc0 += sc[(h*4 + l)*193 + s0 + sl] * kt[sl*129 + c];
      idx = tid + 256;
      l = idx >> 7; c = idx & 127; h = c >> 4;
      #pragma unroll
      for (int sl = 0; sl < 32; sl++)
        acc1 += sc[(h*4 + l)*193 + s0 + sl] * kt[sl*129 + c];
    }
  }
  {
    int idx = tid;
    MSG[qoff + ((size_t)n*192 + l0 + (idx>>7))*128 + (idx & 127)] = acc0;
    idx = tid + 256;
    MSG[qoff + ((size_t)n*192 + l0 + (idx>>7))*128 + (idx & 127)] = acc1;
  }
}

// ---------------- launch ----------------
extern "C" void kernel_launch(void* const* d_in, const int* in_sizes, int n_in,
                              void* d_out, int out_size, void* d_ws, size_t ws_size,
                              hipStream_t stream) {
  // setup_inputs() dict order (sa/ca interleaved); all fp32 per reference:
  const float* feat_l = (const float*)d_in[0];
  const float* feat_r = (const float*)d_in[1];
  const float* attn_l = (const float*)d_in[2];
  const float* attn_r = (const float*)d_in[3];
  const float* sa_w[6] = { (const float*)d_in[4],  (const float*)d_in[6],  (const float*)d_in[8],
                           (const float*)d_in[10], (const float*)d_in[12], (const float*)d_in[14] };
  const float* ca_w[6] = { (const float*)d_in[5],  (const float*)d_in[7],  (const float*)d_in[9],
                           (const float*)d_in[11], (const float*)d_in[13], (const float*)d_in[15] };
  const float* sa_n1g = (const float*)d_in[16]; const float* ca_n1g = (const float*)d_in[17];
  const float* sa_n1b = (const float*)d_in[18]; const float* ca_n1b = (const float*)d_in[19];
  const float* sa_n2g = (const float*)d_in[20]; const float* ca_n2g = (const float*)d_in[21];
  const float* sa_n2b = (const float*)d_in[22]; const float* ca_n2b = (const float*)d_in[23];

  float* F   = (float*)d_ws;       // current features [left;right], 36864x128
  float* B1  = F  + NE;            // xn / msg / mn
  float* B2  = B1 + NE;            // q / mlp-hidden
  float* B3  = B2 + NE;            // k
  float* B4  = B3 + NE;            // v
  float* ALa = B4 + NE;            // attn-left accumulator (fp32)
  float* ARa = ALa + ATTN_E;
  float* KVp = ARa + ATTN_E;       // 32*NCHUNK*272 partials

  k_copy<<<1024, 256, 0, stream>>>(feat_l, F, HALF_E);
  k_copy<<<1024, 256, 0, stream>>>(feat_r, F + HALF_E, HALF_E);
  k_zero<<<2048, 256, 0, stream>>>(ALa, 2*ATTN_E);

  for (int i = 0; i < 6; i++) {
    size_t wo = (size_t)i*128*128;
    int vo = i*128;
    // ---- self layer (both sides share params) ----
    k_ln<<<9216, 256, 0, stream>>>(F, sa_n1g+vo, sa_n1b+vo, B1);
    k_gemm<3><<<576, 256, 0, stream>>>(B1, sa_w[0]+wo, nullptr, B2);  // Q = phi(q)
    k_gemm<3><<<576, 256, 0, stream>>>(B1, sa_w[1]+wo, nullptr, B3);  // K = phi(k)
    k_gemm<0><<<576, 256, 0, stream>>>(B1, sa_w[2]+wo, nullptr, B4);  // V
    k_linred<<<dim3(32, NCHUNK), 256, 0, stream>>>(B3, B4, KVp);
    k_linapply<<<2304, 256, 0, stream>>>(B2, KVp, B1);                // msg
    k_gemm<1><<<576, 256, 0, stream>>>(B1, sa_w[3]+wo, F, F);         // F = F + msg@Wm
    k_ln<<<9216, 256, 0, stream>>>(F, sa_n2g+vo, sa_n2b+vo, B1);
    k_gemm<2><<<576, 256, 0, stream>>>(B1, sa_w[4]+wo, nullptr, B2);  // gelu(mn@W1)
    k_gemm<1><<<576, 256, 0, stream>>>(B2, sa_w[5]+wo, F, F);         // F += h@W2
    // ---- cross layer ----
    k_ln<<<9216, 256, 0, stream>>>(F, ca_n1g+vo, ca_n1b+vo, B1);
    k_gemm<0><<<576, 256, 0, stream>>>(B1, ca_w[0]+wo, nullptr, B2);  // q
    k_gemm<0><<<576, 256, 0, stream>>>(B1, ca_w[1]+wo, nullptr, B3);  // k
    k_gemm<0><<<576, 256, 0, stream>>>(B1, ca_w[2]+wo, nullptr, B4);  // v
    k_fullattn<<<dim3(4608, 2), 256, 0, stream>>>(B2, B3, B4, B1, ALa, ARa);
    k_gemm<1><<<576, 256, 0, stream>>>(B1, ca_w[3]+wo, F, F);
    k_ln<<<9216, 256, 0, stream>>>(F, ca_n2g+vo, ca_n2b+vo, B1);
    k_gemm<2><<<576, 256, 0, stream>>>(B1, ca_w[4]+wo, nullptr, B2);
    k_gemm<1><<<576, 256, 0, stream>>>(B2, ca_w[5]+wo, F, F);
  }

  float* out = (float*)d_out;
  k_copy<<<2048, 256, 0, stream>>>(F, out, NE);                          // fl, fr
  k_addf<<<2048, 256, 0, stream>>>(attn_l, ALa, out + NE, ATTN_E);       // al
  k_addf<<<2048, 256, 0, stream>>>(attn_r, ARa, out + NE + ATTN_E, ATTN_E); // ar
}

// Round 3
// 2557.840 us; speedup vs baseline: 2.8582x; 2.8582x over previous
//
#include <hip/hip_runtime.h>
#include <hip/hip_bf16.h>

using bf16x8 = __attribute__((ext_vector_type(8))) short;
using f32x4  = __attribute__((ext_vector_type(4))) float;

#define NE      4718592          // 36864 rows * 128
#define HALF_R  18432            // rows per side
#define ATTN_E  3538944          // 2*48*192*192
#define SEQ     9216             // rows per linear-attn batch (4 batches)
#define NCHUNK  9

__device__ __forceinline__ float b2f(short s) {
  union { unsigned u; float f; } x; x.u = ((unsigned)(unsigned short)s) << 16; return x.f;
}
__device__ __forceinline__ short f2b(float f) {
  __hip_bfloat16 h = __float2bfloat16(f);
  short s; __builtin_memcpy(&s, &h, 2); return s;
}
__device__ __forceinline__ f32x4 mfma16(bf16x8 a, bf16x8 b, f32x4 c) {
  return __builtin_amdgcn_mfma_f32_16x16x32_bf16(a, b, c, 0, 0, 0);
}

// ---------------- misc ----------------
__global__ void k_copy(const float* __restrict__ in, float* __restrict__ out, int n) {
  for (int i = blockIdx.x*blockDim.x + threadIdx.x; i < n; i += gridDim.x*blockDim.x)
    out[i] = in[i];
}
__global__ void k_zero(float* __restrict__ p, int n) {
  for (int i = blockIdx.x*blockDim.x + threadIdx.x; i < n; i += gridDim.x*blockDim.x)
    p[i] = 0.f;
}
__global__ void k_addf(const float* __restrict__ base, const float* __restrict__ acc,
                       float* __restrict__ out, int n) {
  for (int i = blockIdx.x*blockDim.x + threadIdx.x; i < n; i += gridDim.x*blockDim.x)
    out[i] = base[i] + acc[i];
}
// convert 12 weight tensors [6][128][128] fp32 -> bf16, layout preserved
__global__ void k_w2b(const float* s0, const float* s1, const float* s2, const float* s3,
                      const float* s4, const float* s5, const float* s6, const float* s7,
                      const float* s8, const float* s9, const float* s10, const float* s11,
                      short* __restrict__ dst) {
  const float* srcs[12] = {s0,s1,s2,s3,s4,s5,s6,s7,s8,s9,s10,s11};
  const float* src = srcs[blockIdx.y];
  short* d = dst + (size_t)blockIdx.y*6*16384;
  int i = blockIdx.x*1024 + threadIdx.x*4;   // grid.x = 96 -> 98304 elems
  f32x4 v = *(const f32x4*)(src + i);
  d[i+0] = f2b(v[0]); d[i+1] = f2b(v[1]); d[i+2] = f2b(v[2]); d[i+3] = f2b(v[3]);
}

// ============ MFMA GEMM family: C[M,128] = epi(LN?(A) @ W^T) ============
// A-tile 64 rows/block, 4 waves, W (128x128 bf16) + A staged in LDS with
// XOR granule swizzle; mfma_f32_16x16x32_bf16, fp32 acc.

__device__ __forceinline__ void stage_W(const short* __restrict__ W, short* Ws, int tid) {
  for (int i = tid; i < 128*16; i += 256) {
    int c = i >> 4, g = i & 15;
    bf16x8 w = *(const bf16x8*)(W + c*128 + g*8);
    *(bf16x8*)(&Ws[c*128 + ((g ^ (c & 7))*8)]) = w;
  }
}
// LN(F) rows -> As (bf16, swizzled)
__device__ __forceinline__ void stage_A_ln(const float* __restrict__ F, int row0,
                                           const float* __restrict__ g,
                                           const float* __restrict__ b,
                                           short* As, int tid) {
  int r = tid >> 2, q4 = tid & 3;
  const float* xrow = F + (size_t)(row0 + r)*128 + q4*32;
  float x[32];
  #pragma unroll
  for (int t = 0; t < 8; t++) { f32x4 v = *(const f32x4*)(xrow + t*4);
    x[t*4+0]=v[0]; x[t*4+1]=v[1]; x[t*4+2]=v[2]; x[t*4+3]=v[3]; }
  float s = 0.f, sq = 0.f;
  #pragma unroll
  for (int t = 0; t < 32; t++) { s += x[t]; sq += x[t]*x[t]; }
  s  += __shfl_xor(s, 1, 64);  s  += __shfl_xor(s, 2, 64);
  sq += __shfl_xor(sq, 1, 64); sq += __shfl_xor(sq, 2, 64);
  float mean = s * (1.f/128.f);
  float var  = sq * (1.f/128.f) - mean*mean;
  float inv  = rsqrtf(var + 1e-5f);
  const float* gp = g + q4*32; const float* bp = b + q4*32;
  #pragma unroll
  for (int ii = 0; ii < 4; ii++) {
    short tmp[8];
    #pragma unroll
    for (int j = 0; j < 8; j++) {
      int t = ii*8 + j;
      tmp[j] = f2b((x[t]-mean)*inv*gp[t] + bp[t]);
    }
    bf16x8 pk; __builtin_memcpy(&pk, tmp, 16);
    int gran = (q4*4 + ii) ^ (r & 7);
    *(bf16x8*)(&As[r*128 + gran*8]) = pk;
  }
}
// bf16 A rows -> As (swizzled)
__device__ __forceinline__ void stage_A_bf(const short* __restrict__ A, int row0,
                                           short* As, int tid) {
  for (int i = tid; i < 64*16; i += 256) {
    int r = i >> 4, g = i & 15;
    bf16x8 v = *(const bf16x8*)(A + (size_t)(row0 + r)*128 + g*8);
    *(bf16x8*)(&As[r*128 + ((g ^ (r & 7))*8)]) = v;
  }
}
__device__ __forceinline__ void mfma_core(const short* As, const short* Ws,
                                          int wave, int lane, f32x4 acc[8]) {
  bf16x8 af[4];
  int rl = wave*16 + (lane & 15);
  #pragma unroll
  for (int kc = 0; kc < 4; kc++) {
    int g = (kc*4 + (lane >> 4)) ^ (rl & 7);
    af[kc] = *(const bf16x8*)(&As[rl*128 + g*8]);
  }
  #pragma unroll
  for (int ct = 0; ct < 8; ct++) {
    int c = ct*16 + (lane & 15);
    #pragma unroll
    for (int kc = 0; kc < 4; kc++) {
      int g = (kc*4 + (lane >> 4)) ^ (c & 7);
      bf16x8 bf = *(const bf16x8*)(&Ws[c*128 + g*8]);
      acc[ct] = mfma16(af[kc], bf, acc[ct]);
    }
  }
}

// LN + 3 GEMMs (q,k,v); phi_mask bit y => elu+1 epilogue on output y
__global__ __launch_bounds__(256) void k_qkv(const float* __restrict__ F,
                                             const short* __restrict__ Wq,
                                             const short* __restrict__ Wk,
                                             const short* __restrict__ Wv,
                                             const float* __restrict__ g,
                                             const float* __restrict__ b,
                                             short* __restrict__ Qo,
                                             short* __restrict__ Ko,
                                             short* __restrict__ Vo,
                                             int phi_mask) {
  __shared__ short As[64*128];
  __shared__ short Ws[128*128];
  int tid = threadIdx.x, y = blockIdx.y;
  int row0 = blockIdx.x * 64;
  const short* W = (y == 0) ? Wq : (y == 1) ? Wk : Wv;
  short* OUT = (y == 0) ? Qo : (y == 1) ? Ko : Vo;
  bool phi = (phi_mask >> y) & 1;
  stage_W(W, Ws, tid);
  stage_A_ln(F, row0, g, b, As, tid);
  __syncthreads();
  int wave = tid >> 6, lane = tid & 63;
  f32x4 acc[8] = {};
  mfma_core(As, Ws, wave, lane, acc);
  int rbase = row0 + wave*16 + (lane >> 4)*4;
  int cl = lane & 15;
  #pragma unroll
  for (int ct = 0; ct < 8; ct++)
    #pragma unroll
    for (int reg = 0; reg < 4; reg++) {
      float v = acc[ct][reg];
      if (phi) v = (v > 0.f) ? v + 1.0f : __expf(v);
      OUT[(size_t)(rbase + reg)*128 + ct*16 + cl] = f2b(v);
    }
}

// LN + GEMM + gelu -> bf16
__global__ __launch_bounds__(256) void k_lngemm_gelu(const float* __restrict__ F,
                                                     const short* __restrict__ W,
                                                     const float* __restrict__ g,
                                                     const float* __restrict__ b,
                                                     short* __restrict__ OUT) {
  __shared__ short As[64*128];
  __shared__ short Ws[128*128];
  int tid = threadIdx.x;
  int row0 = blockIdx.x * 64;
  stage_W(W, Ws, tid);
  stage_A_ln(F, row0, g, b, As, tid);
  __syncthreads();
  int wave = tid >> 6, lane = tid & 63;
  f32x4 acc[8] = {};
  mfma_core(As, Ws, wave, lane, acc);
  int rbase = row0 + wave*16 + (lane >> 4)*4;
  int cl = lane & 15;
  #pragma unroll
  for (int ct = 0; ct < 8; ct++)
    #pragma unroll
    for (int reg = 0; reg < 4; reg++) {
      float v = acc[ct][reg];
      v = 0.5f*v*(1.0f + erff(v*0.70710678118654752f));
      OUT[(size_t)(rbase + reg)*128 + ct*16 + cl] = f2b(v);
    }
}

// bf16 A, GEMM, F += result (in-place residual)
__global__ __launch_bounds__(256) void k_gemm_res(const short* __restrict__ A,
                                                  const short* __restrict__ W,
                                                  float* __restrict__ F) {
  __shared__ short As[64*128];
  __shared__ short Ws[128*128];
  int tid = threadIdx.x;
  int row0 = blockIdx.x * 64;
  stage_W(W, Ws, tid);
  stage_A_bf(A, row0, As, tid);
  __syncthreads();
  int wave = tid >> 6, lane = tid & 63;
  f32x4 acc[8] = {};
  mfma_core(As, Ws, wave, lane, acc);
  int rbase = row0 + wave*16 + (lane >> 4)*4;
  int cl = lane & 15;
  #pragma unroll
  for (int ct = 0; ct < 8; ct++)
    #pragma unroll
    for (int reg = 0; reg < 4; reg++) {
      size_t off = (size_t)(rbase + reg)*128 + ct*16 + cl;
      F[off] += acc[ct][reg];
    }
}

// ---------------- linear attention (bf16 in) ----------------
__global__ __launch_bounds__(256) void k_linred(const short* __restrict__ K,
                                                const short* __restrict__ V,
                                                float* __restrict__ kvp) {
  int nh = blockIdx.x;
  int n = nh >> 3, h = nh & 7;
  int chunk = blockIdx.y;
  int r0 = chunk * (SEQ / NCHUNK);
  const short* kb = K + (size_t)n*SEQ*128 + h*16;
  const short* vb = V + (size_t)n*SEQ*128 + h*16;
  __shared__ float ks[16][17], vs[16][17];
  int tid = threadIdx.x;
  int d1 = tid >> 4, d2 = tid & 15;
  float kv = 0.f, ksum = 0.f;
  for (int r = r0; r < r0 + SEQ/NCHUNK; r += 16) {
    __syncthreads();
    int rr = tid >> 4, dd = tid & 15;
    ks[rr][dd] = b2f(kb[(size_t)(r + rr)*128 + dd]);
    vs[rr][dd] = b2f(vb[(size_t)(r + rr)*128 + dd]);
    __syncthreads();
    #pragma unroll
    for (int j = 0; j < 16; j++) {
      float kvl = ks[j][d1];
      kv   += kvl * vs[j][d2];
      ksum += kvl;
    }
  }
  float* dst = kvp + ((size_t)nh*NCHUNK + chunk)*272;
  dst[d1*16 + d2] = kv;
  if (d2 == 0) dst[256 + d1] = ksum;
}

__global__ __launch_bounds__(256) void k_linapply(const short* __restrict__ Q,
                                                  const float* __restrict__ kvp,
                                                  short* __restrict__ MSG) {
  __shared__ float kv[8*272];
  int row0 = blockIdx.x * 16;
  int n = row0 / SEQ;
  int tid = threadIdx.x;
  for (int i = tid; i < 8*272; i += 256) {
    int h = i / 272, j = i % 272;
    const float* src = kvp + ((size_t)(n*8 + h)*NCHUNK)*272 + j;
    float s = 0.f;
    #pragma unroll
    for (int c2 = 0; c2 < NCHUNK; c2++) s += src[(size_t)c2*272];
    kv[i] = s;
  }
  __syncthreads();
  #pragma unroll
  for (int p = 0; p < 8; p++) {
    int idx = tid + p*256;
    int rl = idx >> 7, c = idx & 127;
    int h = c >> 4, d = c & 15;
    int row = row0 + rl;
    const short* qr = Q + (size_t)row*128 + h*16;
    float z = 1e-6f, o = 0.f;
    #pragma unroll
    for (int dd = 0; dd < 16; dd++) {
      float qv = b2f(qr[dd]);
      z += qv * kv[h*272 + 256 + dd];
      o += qv * kv[h*272 + dd*16 + d];
    }
    MSG[(size_t)row*128 + c] = f2b(o / z);
  }
}

// ---------------- full attention: flash-style, 32 q-rows/block ----------------
// thread (l = tid>>3, h = tid&7) owns one (q-row, head). K/V fp32 in LDS,
// head-slice stride 20 floats (16B-aligned, conflict-free with broadcast).
__global__ __launch_bounds__(256) void k_fullattn(const short* __restrict__ Q,
                                                  const short* __restrict__ K,
                                                  const short* __restrict__ V,
                                                  short* __restrict__ MSG,
                                                  float* __restrict__ AL,
                                                  float* __restrict__ AR) {
  int side = blockIdx.y;
  int n  = blockIdx.x / 6;
  int l0 = (blockIdx.x % 6) * 32;
  int qbase = side*HALF_R + n*192;
  int kbase = (side^1)*HALF_R + n*192;

  __shared__ float Ks[32*160];
  __shared__ float Vs[32*160];

  int tid = threadIdx.x;
  int l = tid >> 3, h = tid & 7;

  const short* qp = Q + (size_t)(qbase + l0 + l)*128 + h*16;
  float q[16];
  {
    bf16x8 q0 = *(const bf16x8*)qp, q1 = *(const bf16x8*)(qp + 8);
    #pragma unroll
    for (int i = 0; i < 8; i++) { q[i] = b2f(q0[i]) * 0.25f; q[8+i] = b2f(q1[i]) * 0.25f; }
  }

  float m = -1e30f, lsum = 0.f, o[16];
  #pragma unroll
  for (int d = 0; d < 16; d++) o[d] = 0.f;

  for (int s0 = 0; s0 < 192; s0 += 32) {
    __syncthreads();
    for (int i = tid; i < 4096; i += 256) {
      int r = i >> 7, c = i & 127;
      int off = r*160 + (c >> 4)*20 + (c & 15);
      Ks[off] = b2f(K[(size_t)(kbase + s0 + r)*128 + c]);
      Vs[off] = b2f(V[(size_t)(kbase + s0 + r)*128 + c]);
    }
    __syncthreads();
    float s[32];
    float tmax = m;
    const float* kh = Ks + h*20;
    #pragma unroll
    for (int j = 0; j < 32; j++) {
      const f32x4* kr = (const f32x4*)(kh + j*160);
      float d0 = 0.f;
      #pragma unroll
      for (int t = 0; t < 4; t++) {
        f32x4 kvv = kr[t];
        d0 += q[t*4+0]*kvv[0] + q[t*4+1]*kvv[1] + q[t*4+2]*kvv[2] + q[t*4+3]*kvv[3];
      }
      s[j] = d0;
      tmax = fmaxf(tmax, d0);
    }
    float sc = __expf(m - tmax);
    lsum *= sc;
    #pragma unroll
    for (int d = 0; d < 16; d++) o[d] *= sc;
    m = tmax;
    const float* vh = Vs + h*20;
    #pragma unroll
    for (int j = 0; j < 32; j++) {
      float p = __expf(s[j] - m);
      lsum += p;
      const f32x4* vr = (const f32x4*)(vh + j*160);
      #pragma unroll
      for (int t = 0; t < 4; t++) {
        f32x4 vv = vr[t];
        o[t*4+0] += p*vv[0]; o[t*4+1] += p*vv[1]; o[t*4+2] += p*vv[2]; o[t*4+3] += p*vv[3];
      }
    }
  }
  float inv = 1.f / lsum;
  {
    short* mp = MSG + (size_t)(qbase + l0 + l)*128 + h*16;
    short tmp[16];
    #pragma unroll
    for (int d = 0; d < 16; d++) tmp[d] = f2b(o[d] * inv);
    bf16x8 p0, p1; __builtin_memcpy(&p0, tmp, 16); __builtin_memcpy(&p1, tmp+8, 16);
    *(bf16x8*)mp = p0; *(bf16x8*)(mp + 8) = p1;
  }

  // pass 2: raw[l][s] += sum_h exp(s_ls - m)/lsum
  float* rawp = (side ? AR : AL) + (size_t)(n*192 + l0)*192;
  for (int s0 = 0; s0 < 192; s0 += 32) {
    __syncthreads();
    for (int i = tid; i < 4096; i += 256) {
      int r = i >> 7, c = i & 127;
      Ks[r*160 + (c >> 4)*20 + (c & 15)] = b2f(K[(size_t)(kbase + s0 + r)*128 + c]);
    }
    __syncthreads();
    const float* kh = Ks + h*20;
    #pragma unroll
    for (int j = 0; j < 32; j++) {
      const f32x4* kr = (const f32x4*)(kh + j*160);
      float d0 = 0.f;
      #pragma unroll
      for (int t = 0; t < 4; t++) {
        f32x4 kvv = kr[t];
        d0 += q[t*4+0]*kvv[0] + q[t*4+1]*kvv[1] + q[t*4+2]*kvv[2] + q[t*4+3]*kvv[3];
      }
      float a = __expf(d0 - m) * inv;
      a += __shfl_xor(a, 1, 64);
      a += __shfl_xor(a, 2, 64);
      a += __shfl_xor(a, 4, 64);
      if (h == 0) rawp[l*192 + s0 + j] += a;
    }
  }
}

// ---------------- launch ----------------
extern "C" void kernel_launch(void* const* d_in, const int* in_sizes, int n_in,
                              void* d_out, int out_size, void* d_ws, size_t ws_size,
                              hipStream_t stream) {
  const float* feat_l = (const float*)d_in[0];
  const float* feat_r = (const float*)d_in[1];
  const float* attn_l = (const float*)d_in[2];
  const float* attn_r = (const float*)d_in[3];
  const float* saw[6] = { (const float*)d_in[4],  (const float*)d_in[6],  (const float*)d_in[8],
                          (const float*)d_in[10], (const float*)d_in[12], (const float*)d_in[14] };
  const float* caw[6] = { (const float*)d_in[5],  (const float*)d_in[7],  (const float*)d_in[9],
                          (const float*)d_in[11], (const float*)d_in[13], (const float*)d_in[15] };
  const float* sa_n1g = (const float*)d_in[16]; const float* ca_n1g = (const float*)d_in[17];
  const float* sa_n1b = (const float*)d_in[18]; const float* ca_n1b = (const float*)d_in[19];
  const float* sa_n2g = (const float*)d_in[20]; const float* ca_n2g = (const float*)d_in[21];
  const float* sa_n2b = (const float*)d_in[22]; const float* ca_n2b = (const float*)d_in[23];

  float* F   = (float*)d_ws;                 // fp32 residual
  float* ALa = F + NE;
  float* ARa = ALa + ATTN_E;
  float* KVp = ARa + ATTN_E;                 // 32*9*272
  short* WB  = (short*)(KVp + 32*NCHUNK*272);// 12*6*16384 bf16
  short* Qb  = WB + 12*6*16384;
  short* Kb  = Qb + NE;
  short* Vb  = Kb + NE;
  short* Mb  = Vb + NE;                      // msg
  short* Hb  = Mb + NE;                      // mlp hidden

  k_w2b<<<dim3(96,12), 256, 0, stream>>>(saw[0],saw[1],saw[2],saw[3],saw[4],saw[5],
                                         caw[0],caw[1],caw[2],caw[3],caw[4],caw[5], WB);
  k_copy<<<1024, 256, 0, stream>>>(feat_l, F, NE/2);
  k_copy<<<1024, 256, 0, stream>>>(feat_r, F + NE/2, NE/2);
  k_zero<<<2048, 256, 0, stream>>>(ALa, 2*ATTN_E);

  for (int i = 0; i < 6; i++) {
    const short* sw[6], *cw[6];
    for (int t = 0; t < 6; t++) { sw[t] = WB + (size_t)(t*6 + i)*16384; cw[t] = WB + (size_t)((6+t)*6 + i)*16384; }
    int vo = i*128;
    // ---- self layer ----
    k_qkv<<<dim3(576,3), 256, 0, stream>>>(F, sw[0], sw[1], sw[2], sa_n1g+vo, sa_n1b+vo,
                                           Qb, Kb, Vb, 0b011);
    k_linred<<<dim3(32, NCHUNK), 256, 0, stream>>>(Kb, Vb, KVp);
    k_linapply<<<2304, 256, 0, stream>>>(Qb, KVp, Mb);
    k_gemm_res<<<576, 256, 0, stream>>>(Mb, sw[3], F);
    k_lngemm_gelu<<<576, 256, 0, stream>>>(F, sw[4], sa_n2g+vo, sa_n2b+vo, Hb);
    k_gemm_res<<<576, 256, 0, stream>>>(Hb, sw[5], F);
    // ---- cross layer ----
    k_qkv<<<dim3(576,3), 256, 0, stream>>>(F, cw[0], cw[1], cw[2], ca_n1g+vo, ca_n1b+vo,
                                           Qb, Kb, Vb, 0);
    k_fullattn<<<dim3(576, 2), 256, 0, stream>>>(Qb, Kb, Vb, Mb, ALa, ARa);
    k_gemm_res<<<576, 256, 0, stream>>>(Mb, cw[3], F);
    k_lngemm_gelu<<<576, 256, 0, stream>>>(F, cw[4], ca_n2g+vo, ca_n2b+vo, Hb);
    k_gemm_res<<<576, 256, 0, stream>>>(Hb, cw[5], F);
  }

  float* out = (float*)d_out;
  k_copy<<<2048, 256, 0, stream>>>(F, out, NE);
  k_addf<<<2048, 256, 0, stream>>>(attn_l, ALa, out + NE, ATTN_E);
  k_addf<<<2048, 256, 0, stream>>>(attn_r, ARa, out + NE + ATTN_E, ATTN_E);
}

// Round 4
// 1564.729 us; speedup vs baseline: 4.6723x; 1.6347x over previous
//
#include <hip/hip_runtime.h>
#include <hip/hip_bf16.h>

using bf16x8 = __attribute__((ext_vector_type(8))) short;
using bf16x4 = __attribute__((ext_vector_type(4))) short;
using f32x4  = __attribute__((ext_vector_type(4))) float;

#define NE      4718592          // 36864 rows * 128
#define HALF_R  18432            // rows per side
#define ATTN_E  3538944          // 2*48*192*192
#define SEQ     9216             // rows per linear-attn batch (4 batches)
#define NCHUNK  9

__device__ __forceinline__ float b2f(short s) {
  union { unsigned u; float f; } x; x.u = ((unsigned)(unsigned short)s) << 16; return x.f;
}
__device__ __forceinline__ short f2b(float f) {
  __hip_bfloat16 h = __float2bfloat16(f);
  short s; __builtin_memcpy(&s, &h, 2); return s;
}
__device__ __forceinline__ f32x4 mfma16(bf16x8 a, bf16x8 b, f32x4 c) {
  return __builtin_amdgcn_mfma_f32_16x16x32_bf16(a, b, c, 0, 0, 0);
}
// 16x16x16 bf16 MFMA (K=16): builtin if present, else inline asm
__device__ __forceinline__ f32x4 mfma16k16(bf16x4 a, bf16x4 b, f32x4 c) {
#if __has_builtin(__builtin_amdgcn_mfma_f32_16x16x16bf16_1k)
  return __builtin_amdgcn_mfma_f32_16x16x16bf16_1k(a, b, c, 0, 0, 0);
#else
  f32x4 d;
  asm("v_mfma_f32_16x16x16_bf16 %0, %1, %2, %3" : "=v"(d) : "v"(a), "v"(b), "v"(c));
  return d;
#endif
}

// ---------------- misc ----------------
__global__ void k_copy(const float* __restrict__ in, float* __restrict__ out, int n) {
  for (int i = blockIdx.x*blockDim.x + threadIdx.x; i < n; i += gridDim.x*blockDim.x)
    out[i] = in[i];
}
__global__ void k_zero(float* __restrict__ p, int n) {
  for (int i = blockIdx.x*blockDim.x + threadIdx.x; i < n; i += gridDim.x*blockDim.x)
    p[i] = 0.f;
}
__global__ void k_addf(const float* __restrict__ base, const float* __restrict__ acc,
                       float* __restrict__ out, int n) {
  for (int i = blockIdx.x*blockDim.x + threadIdx.x; i < n; i += gridDim.x*blockDim.x)
    out[i] = base[i] + acc[i];
}
// convert 12 weight tensors [6][128][128] fp32 -> bf16
__global__ void k_w2b(const float* s0, const float* s1, const float* s2, const float* s3,
                      const float* s4, const float* s5, const float* s6, const float* s7,
                      const float* s8, const float* s9, const float* s10, const float* s11,
                      short* __restrict__ dst) {
  const float* srcs[12] = {s0,s1,s2,s3,s4,s5,s6,s7,s8,s9,s10,s11};
  const float* src = srcs[blockIdx.y];
  short* d = dst + (size_t)blockIdx.y*6*16384;
  int i = blockIdx.x*1024 + threadIdx.x*4;
  f32x4 v = *(const f32x4*)(src + i);
  d[i+0] = f2b(v[0]); d[i+1] = f2b(v[1]); d[i+2] = f2b(v[2]); d[i+3] = f2b(v[3]);
}

// ============ MFMA GEMM family ============
__device__ __forceinline__ void stage_W(const short* __restrict__ W, short* Ws, int tid) {
  for (int i = tid; i < 128*16; i += 256) {
    int c = i >> 4, g = i & 15;
    bf16x8 w = *(const bf16x8*)(W + c*128 + g*8);
    *(bf16x8*)(&Ws[c*128 + ((g ^ (c & 7))*8)]) = w;
  }
}
__device__ __forceinline__ void stage_A_ln(const float* __restrict__ F, int row0,
                                           const float* __restrict__ g,
                                           const float* __restrict__ b,
                                           short* As, int tid) {
  int r = tid >> 2, q4 = tid & 3;
  const float* xrow = F + (size_t)(row0 + r)*128 + q4*32;
  float x[32];
  #pragma unroll
  for (int t = 0; t < 8; t++) { f32x4 v = *(const f32x4*)(xrow + t*4);
    x[t*4+0]=v[0]; x[t*4+1]=v[1]; x[t*4+2]=v[2]; x[t*4+3]=v[3]; }
  float s = 0.f, sq = 0.f;
  #pragma unroll
  for (int t = 0; t < 32; t++) { s += x[t]; sq += x[t]*x[t]; }
  s  += __shfl_xor(s, 1, 64);  s  += __shfl_xor(s, 2, 64);
  sq += __shfl_xor(sq, 1, 64); sq += __shfl_xor(sq, 2, 64);
  float mean = s * (1.f/128.f);
  float var  = sq * (1.f/128.f) - mean*mean;
  float inv  = rsqrtf(var + 1e-5f);
  const float* gp = g + q4*32; const float* bp = b + q4*32;
  #pragma unroll
  for (int ii = 0; ii < 4; ii++) {
    short tmp[8];
    #pragma unroll
    for (int j = 0; j < 8; j++) {
      int t = ii*8 + j;
      tmp[j] = f2b((x[t]-mean)*inv*gp[t] + bp[t]);
    }
    bf16x8 pk; __builtin_memcpy(&pk, tmp, 16);
    int gran = (q4*4 + ii) ^ (r & 7);
    *(bf16x8*)(&As[r*128 + gran*8]) = pk;
  }
}
__device__ __forceinline__ void stage_A_bf(const short* __restrict__ A, int row0,
                                           short* As, int tid) {
  for (int i = tid; i < 64*16; i += 256) {
    int r = i >> 4, g = i & 15;
    bf16x8 v = *(const bf16x8*)(A + (size_t)(row0 + r)*128 + g*8);
    *(bf16x8*)(&As[r*128 + ((g ^ (r & 7))*8)]) = v;
  }
}
__device__ __forceinline__ void mfma_core(const short* As, const short* Ws,
                                          int wave, int lane, f32x4 acc[8]) {
  bf16x8 af[4];
  int rl = wave*16 + (lane & 15);
  #pragma unroll
  for (int kc = 0; kc < 4; kc++) {
    int g = (kc*4 + (lane >> 4)) ^ (rl & 7);
    af[kc] = *(const bf16x8*)(&As[rl*128 + g*8]);
  }
  #pragma unroll
  for (int ct = 0; ct < 8; ct++) {
    int c = ct*16 + (lane & 15);
    #pragma unroll
    for (int kc = 0; kc < 4; kc++) {
      int g = (kc*4 + (lane >> 4)) ^ (c & 7);
      bf16x8 bf = *(const bf16x8*)(&Ws[c*128 + g*8]);
      acc[ct] = mfma16(af[kc], bf, acc[ct]);
    }
  }
}

// LN + 3 GEMMs (q,k,v); phi_mask bit y => elu+1; q scaled by qscale
__global__ __launch_bounds__(256) void k_qkv(const float* __restrict__ F,
                                             const short* __restrict__ Wq,
                                             const short* __restrict__ Wk,
                                             const short* __restrict__ Wv,
                                             const float* __restrict__ g,
                                             const float* __restrict__ b,
                                             short* __restrict__ Qo,
                                             short* __restrict__ Ko,
                                             short* __restrict__ Vo,
                                             int phi_mask, float qscale) {
  __shared__ short As[64*128];
  __shared__ short Ws[128*128];
  int tid = threadIdx.x, y = blockIdx.y;
  int row0 = blockIdx.x * 64;
  const short* W = (y == 0) ? Wq : (y == 1) ? Wk : Wv;
  short* OUT = (y == 0) ? Qo : (y == 1) ? Ko : Vo;
  bool phi = (phi_mask >> y) & 1;
  float sc = (y == 0) ? qscale : 1.0f;
  stage_W(W, Ws, tid);
  stage_A_ln(F, row0, g, b, As, tid);
  __syncthreads();
  int wave = tid >> 6, lane = tid & 63;
  f32x4 acc[8] = {};
  mfma_core(As, Ws, wave, lane, acc);
  int rbase = row0 + wave*16 + (lane >> 4)*4;
  int cl = lane & 15;
  #pragma unroll
  for (int ct = 0; ct < 8; ct++)
    #pragma unroll
    for (int reg = 0; reg < 4; reg++) {
      float v = acc[ct][reg] * sc;
      if (phi) v = (v > 0.f) ? v + 1.0f : __expf(v);
      OUT[(size_t)(rbase + reg)*128 + ct*16 + cl] = f2b(v);
    }
}

__global__ __launch_bounds__(256) void k_lngemm_gelu(const float* __restrict__ F,
                                                     const short* __restrict__ W,
                                                     const float* __restrict__ g,
                                                     const float* __restrict__ b,
                                                     short* __restrict__ OUT) {
  __shared__ short As[64*128];
  __shared__ short Ws[128*128];
  int tid = threadIdx.x;
  int row0 = blockIdx.x * 64;
  stage_W(W, Ws, tid);
  stage_A_ln(F, row0, g, b, As, tid);
  __syncthreads();
  int wave = tid >> 6, lane = tid & 63;
  f32x4 acc[8] = {};
  mfma_core(As, Ws, wave, lane, acc);
  int rbase = row0 + wave*16 + (lane >> 4)*4;
  int cl = lane & 15;
  #pragma unroll
  for (int ct = 0; ct < 8; ct++)
    #pragma unroll
    for (int reg = 0; reg < 4; reg++) {
      float v = acc[ct][reg];
      v = 0.5f*v*(1.0f + erff(v*0.70710678118654752f));
      OUT[(size_t)(rbase + reg)*128 + ct*16 + cl] = f2b(v);
    }
}

__global__ __launch_bounds__(256) void k_gemm_res(const short* __restrict__ A,
                                                  const short* __restrict__ W,
                                                  float* __restrict__ F) {
  __shared__ short As[64*128];
  __shared__ short Ws[128*128];
  int tid = threadIdx.x;
  int row0 = blockIdx.x * 64;
  stage_W(W, Ws, tid);
  stage_A_bf(A, row0, As, tid);
  __syncthreads();
  int wave = tid >> 6, lane = tid & 63;
  f32x4 acc[8] = {};
  mfma_core(As, Ws, wave, lane, acc);
  int rbase = row0 + wave*16 + (lane >> 4)*4;
  int cl = lane & 15;
  #pragma unroll
  for (int ct = 0; ct < 8; ct++)
    #pragma unroll
    for (int reg = 0; reg < 4; reg++) {
      size_t off = (size_t)(rbase + reg)*128 + ct*16 + cl;
      F[off] += acc[ct][reg];
    }
}

// ---------------- linear attention ----------------
__global__ __launch_bounds__(256) void k_linred(const short* __restrict__ K,
                                                const short* __restrict__ V,
                                                float* __restrict__ kvp) {
  int nh = blockIdx.x;
  int n = nh >> 3, h = nh & 7;
  int chunk = blockIdx.y;
  int r0 = chunk * (SEQ / NCHUNK);
  const short* kb = K + (size_t)n*SEQ*128 + h*16;
  const short* vb = V + (size_t)n*SEQ*128 + h*16;
  __shared__ float ks[16][17], vs[16][17];
  int tid = threadIdx.x;
  int d1 = tid >> 4, d2 = tid & 15;
  float kv = 0.f, ksum = 0.f;
  for (int r = r0; r < r0 + SEQ/NCHUNK; r += 16) {
    __syncthreads();
    int rr = tid >> 4, dd = tid & 15;
    ks[rr][dd] = b2f(kb[(size_t)(r + rr)*128 + dd]);
    vs[rr][dd] = b2f(vb[(size_t)(r + rr)*128 + dd]);
    __syncthreads();
    #pragma unroll
    for (int j = 0; j < 16; j++) {
      float kvl = ks[j][d1];
      kv   += kvl * vs[j][d2];
      ksum += kvl;
    }
  }
  float* dst = kvp + ((size_t)nh*NCHUNK + chunk)*272;
  dst[d1*16 + d2] = kv;
  if (d2 == 0) dst[256 + d1] = ksum;
}

__global__ __launch_bounds__(256) void k_linapply(const short* __restrict__ Q,
                                                  const float* __restrict__ kvp,
                                                  short* __restrict__ MSG) {
  __shared__ float kv[8*272];
  int row0 = blockIdx.x * 16;
  int n = row0 / SEQ;
  int tid = threadIdx.x;
  for (int i = tid; i < 8*272; i += 256) {
    int h = i / 272, j = i % 272;
    const float* src = kvp + ((size_t)(n*8 + h)*NCHUNK)*272 + j;
    float s = 0.f;
    #pragma unroll
    for (int c2 = 0; c2 < NCHUNK; c2++) s += src[(size_t)c2*272];
    kv[i] = s;
  }
  __syncthreads();
  #pragma unroll
  for (int p = 0; p < 8; p++) {
    int idx = tid + p*256;
    int rl = idx >> 7, c = idx & 127;
    int h = c >> 4, d = c & 15;
    int row = row0 + rl;
    const short* qr = Q + (size_t)row*128 + h*16;
    float z = 1e-6f, o = 0.f;
    #pragma unroll
    for (int dd = 0; dd < 16; dd++) {
      float qv = b2f(qr[dd]);
      z += qv * kv[h*272 + 256 + dd];
      o += qv * kv[h*272 + dd*16 + d];
    }
    MSG[(size_t)row*128 + c] = f2b(o / z);
  }
}

// ---------------- full attention: MFMA, swapped-operand, per-(side,n) block ----
// 4 waves x 2 heads. S^T = mfma16x16x16(K-frag, Q-frag): D-layout of S^T equals
// the B-frag layout needed by PV (O^T = mfma(Vt-frag, P^T-frag)).
__global__ __launch_bounds__(256) void k_fullattn(const short* __restrict__ Q,
                                                  const short* __restrict__ K,
                                                  const short* __restrict__ V,
                                                  short* __restrict__ MSG,
                                                  float* __restrict__ AL,
                                                  float* __restrict__ AR) {
  __shared__ short Ks[192*128];      // swizzled: elem = s*128 + ((g ^ (s&15))*4)+e
  __shared__ short Vt[128*204];      // transposed V: Vt[d][s], stride 204
  __shared__ float rawb[4*12*64*4];  // [wave][s-tile][lane] f32x4
  int side = blockIdx.y;
  int n = blockIdx.x;
  int qbase = side*HALF_R + n*192;
  int kbase = (side^1)*HALF_R + n*192;
  float* rawbase = (side ? AR : AL) + (size_t)n*192*192;
  int tid = threadIdx.x;
  int wave = tid >> 6, lane = tid & 63;
  int lrow = lane & 15, lgrp = lane >> 4;

  // stage K (swizzled) + V transposed
  #pragma unroll
  for (int i = 0; i < 12; i++) {
    int c = tid + 256*i;            // 3072 chunks of 8 elems
    int s = c >> 4, t8 = c & 15;
    bf16x8 k8 = *(const bf16x8*)(K + (size_t)(kbase + s)*128 + t8*8);
    bf16x4 lo, hi;
    __builtin_memcpy(&lo, &k8, 8);
    __builtin_memcpy(&hi, ((const char*)&k8) + 8, 8);
    *(bf16x4*)(&Ks[s*128 + (((2*t8)   ^ (s & 15))*4)]) = lo;
    *(bf16x4*)(&Ks[s*128 + (((2*t8+1) ^ (s & 15))*4)]) = hi;
    bf16x8 v8 = *(const bf16x8*)(V + (size_t)(kbase + s)*128 + t8*8);
    #pragma unroll
    for (int j = 0; j < 8; j++) Vt[(t8*8 + j)*204 + s] = v8[j];
  }
  __syncthreads();

  const f32x4 z4 = {0.f, 0.f, 0.f, 0.f};
  for (int lt = 0; lt < 12; lt++) {
    int l0 = lt*16;
    f32x4 sa[2][12];
    #pragma unroll
    for (int hh = 0; hh < 2; hh++) {
      int h = wave*2 + hh;
      bf16x4 qf = *(const bf16x4*)(Q + (size_t)(qbase + l0 + lrow)*128 + h*16 + lgrp*4);
      int g = h*4 + lgrp;
      #pragma unroll
      for (int st = 0; st < 12; st++) {
        bf16x4 kf = *(const bf16x4*)(&Ks[(st*16 + lrow)*128 + ((g ^ lrow)*4)]);
        sa[hh][st] = mfma16k16(kf, qf, z4);
      }
    }
    // softmax over s (rows of S^T) for each l (col, = lrow lane pos)
    #pragma unroll
    for (int hh = 0; hh < 2; hh++) {
      float m = -1e30f;
      #pragma unroll
      for (int st = 0; st < 12; st++)
        m = fmaxf(m, fmaxf(fmaxf(sa[hh][st][0], sa[hh][st][1]),
                           fmaxf(sa[hh][st][2], sa[hh][st][3])));
      m = fmaxf(m, __shfl_xor(m, 16, 64));
      m = fmaxf(m, __shfl_xor(m, 32, 64));
      float sum = 0.f;
      #pragma unroll
      for (int st = 0; st < 12; st++) {
        #pragma unroll
        for (int r = 0; r < 4; r++) {
          float p = __expf(sa[hh][st][r] - m);
          sa[hh][st][r] = p; sum += p;
        }
      }
      sum += __shfl_xor(sum, 16, 64);
      sum += __shfl_xor(sum, 32, 64);
      float inv = 1.f / sum;
      #pragma unroll
      for (int st = 0; st < 12; st++) {
        sa[hh][st][0] *= inv; sa[hh][st][1] *= inv;
        sa[hh][st][2] *= inv; sa[hh][st][3] *= inv;
      }
    }
    // raw partial: sum of this wave's 2 heads
    #pragma unroll
    for (int st = 0; st < 12; st++) {
      f32x4 rsum = sa[0][st] + sa[1][st];
      *(f32x4*)(&rawb[(((wave*12) + st)*64 + lane)*4]) = rsum;
    }
    // PV: O^T = sum_st mfma(Vt-frag, P^T-frag)
    #pragma unroll
    for (int hh = 0; hh < 2; hh++) {
      int h = wave*2 + hh;
      f32x4 o = z4;
      #pragma unroll
      for (int st = 0; st < 12; st++) {
        bf16x4 vf = *(const bf16x4*)(&Vt[(h*16 + lrow)*204 + st*16 + lgrp*4]);
        bf16x4 pf;
        pf[0] = f2b(sa[hh][st][0]); pf[1] = f2b(sa[hh][st][1]);
        pf[2] = f2b(sa[hh][st][2]); pf[3] = f2b(sa[hh][st][3]);
        o = mfma16k16(vf, pf, o);
      }
      bf16x4 o4;
      o4[0] = f2b(o[0]); o4[1] = f2b(o[1]); o4[2] = f2b(o[2]); o4[3] = f2b(o[3]);
      *(bf16x4*)(MSG + (size_t)(qbase + l0 + lrow)*128 + h*16 + lgrp*4) = o4;
    }
    __syncthreads();           // rawb complete
    // reduce rawb (4 waves) -> global raw accumulator
    #pragma unroll
    for (int i = 0; i < 3; i++) {
      int slot = tid + 256*i;  // 768 slots
      int st = slot >> 6, p = slot & 63;
      f32x4 a = *(const f32x4*)(&rawb[((0*12 + st)*64 + p)*4]);
      f32x4 b = *(const f32x4*)(&rawb[((1*12 + st)*64 + p)*4]);
      f32x4 c = *(const f32x4*)(&rawb[((2*12 + st)*64 + p)*4]);
      f32x4 d = *(const f32x4*)(&rawb[((3*12 + st)*64 + p)*4]);
      f32x4 t = (a + b) + (c + d);
      float* gp = rawbase + (size_t)(l0 + (p & 15))*192 + st*16 + ((p >> 4)*4);
      f32x4 cur = *(const f32x4*)gp;
      *(f32x4*)gp = cur + t;
    }
    __syncthreads();           // before next lt overwrites rawb
  }
}

// ---------------- launch ----------------
extern "C" void kernel_launch(void* const* d_in, const int* in_sizes, int n_in,
                              void* d_out, int out_size, void* d_ws, size_t ws_size,
                              hipStream_t stream) {
  const float* feat_l = (const float*)d_in[0];
  const float* feat_r = (const float*)d_in[1];
  const float* attn_l = (const float*)d_in[2];
  const float* attn_r = (const float*)d_in[3];
  const float* saw[6] = { (const float*)d_in[4],  (const float*)d_in[6],  (const float*)d_in[8],
                          (const float*)d_in[10], (const float*)d_in[12], (const float*)d_in[14] };
  const float* caw[6] = { (const float*)d_in[5],  (const float*)d_in[7],  (const float*)d_in[9],
                          (const float*)d_in[11], (const float*)d_in[13], (const float*)d_in[15] };
  const float* sa_n1g = (const float*)d_in[16]; const float* ca_n1g = (const float*)d_in[17];
  const float* sa_n1b = (const float*)d_in[18]; const float* ca_n1b = (const float*)d_in[19];
  const float* sa_n2g = (const float*)d_in[20]; const float* ca_n2g = (const float*)d_in[21];
  const float* sa_n2b = (const float*)d_in[22]; const float* ca_n2b = (const float*)d_in[23];

  float* F   = (float*)d_ws;
  float* ALa = F + NE;
  float* ARa = ALa + ATTN_E;
  float* KVp = ARa + ATTN_E;
  short* WB  = (short*)(KVp + 32*NCHUNK*272);
  short* Qb  = WB + 12*6*16384;
  short* Kb  = Qb + NE;
  short* Vb  = Kb + NE;
  short* Mb  = Vb + NE;
  short* Hb  = Mb + NE;

  k_w2b<<<dim3(96,12), 256, 0, stream>>>(saw[0],saw[1],saw[2],saw[3],saw[4],saw[5],
                                         caw[0],caw[1],caw[2],caw[3],caw[4],caw[5], WB);
  k_copy<<<1024, 256, 0, stream>>>(feat_l, F, NE/2);
  k_copy<<<1024, 256, 0, stream>>>(feat_r, F + NE/2, NE/2);
  k_zero<<<2048, 256, 0, stream>>>(ALa, 2*ATTN_E);

  for (int i = 0; i < 6; i++) {
    const short* sw[6], *cw[6];
    for (int t = 0; t < 6; t++) { sw[t] = WB + (size_t)(t*6 + i)*16384; cw[t] = WB + (size_t)((6+t)*6 + i)*16384; }
    int vo = i*128;
    // ---- self layer ----
    k_qkv<<<dim3(576,3), 256, 0, stream>>>(F, sw[0], sw[1], sw[2], sa_n1g+vo, sa_n1b+vo,
                                           Qb, Kb, Vb, 0b011, 1.0f);
    k_linred<<<dim3(32, NCHUNK), 256, 0, stream>>>(Kb, Vb, KVp);
    k_linapply<<<2304, 256, 0, stream>>>(Qb, KVp, Mb);
    k_gemm_res<<<576, 256, 0, stream>>>(Mb, sw[3], F);
    k_lngemm_gelu<<<576, 256, 0, stream>>>(F, sw[4], sa_n2g+vo, sa_n2b+vo, Hb);
    k_gemm_res<<<576, 256, 0, stream>>>(Hb, sw[5], F);
    // ---- cross layer ----
    k_qkv<<<dim3(576,3), 256, 0, stream>>>(F, cw[0], cw[1], cw[2], ca_n1g+vo, ca_n1b+vo,
                                           Qb, Kb, Vb, 0, 0.25f);
    k_fullattn<<<dim3(96, 2), 256, 0, stream>>>(Qb, Kb, Vb, Mb, ALa, ARa);
    k_gemm_res<<<576, 256, 0, stream>>>(Mb, cw[3], F);
    k_lngemm_gelu<<<576, 256, 0, stream>>>(F, cw[4], ca_n2g+vo, ca_n2b+vo, Hb);
    k_gemm_res<<<576, 256, 0, stream>>>(Hb, cw[5], F);
  }

  float* out = (float*)d_out;
  k_copy<<<2048, 256, 0, stream>>>(F, out, NE);
  k_addf<<<2048, 256, 0, stream>>>(attn_l, ALa, out + NE, ATTN_E);
  k_addf<<<2048, 256, 0, stream>>>(attn_r, ARa, out + NE + ATTN_E, ATTN_E);
}

// Round 5
// 1370.233 us; speedup vs baseline: 5.3355x; 1.1419x over previous
//
#include <hip/hip_runtime.h>
#include <hip/hip_bf16.h>

using bf16x8 = __attribute__((ext_vector_type(8))) short;
using bf16x4 = __attribute__((ext_vector_type(4))) short;
using f32x4  = __attribute__((ext_vector_type(4))) float;

#define NE      4718592          // 36864 rows * 128
#define HALF_R  18432            // rows per side
#define ATTN_E  3538944          // 2*48*192*192
#define SEQ     9216             // rows per linear-attn batch (4 batches)
#define NCHUNK  9

__device__ __forceinline__ float b2f(short s) {
  union { unsigned u; float f; } x; x.u = ((unsigned)(unsigned short)s) << 16; return x.f;
}
__device__ __forceinline__ short f2b(float f) {
  __hip_bfloat16 h = __float2bfloat16(f);
  short s; __builtin_memcpy(&s, &h, 2); return s;
}
__device__ __forceinline__ f32x4 mfma16(bf16x8 a, bf16x8 b, f32x4 c) {
  return __builtin_amdgcn_mfma_f32_16x16x32_bf16(a, b, c, 0, 0, 0);
}
__device__ __forceinline__ f32x4 mfma16k16(bf16x4 a, bf16x4 b, f32x4 c) {
#if __has_builtin(__builtin_amdgcn_mfma_f32_16x16x16bf16_1k)
  return __builtin_amdgcn_mfma_f32_16x16x16bf16_1k(a, b, c, 0, 0, 0);
#else
  f32x4 d;
  asm("v_mfma_f32_16x16x16_bf16 %0, %1, %2, %3" : "=v"(d) : "v"(a), "v"(b), "v"(c));
  return d;
#endif
}

// ---------------- misc ----------------
__global__ void k_copy(const float* __restrict__ in, float* __restrict__ out, int n) {
  for (int i = blockIdx.x*blockDim.x + threadIdx.x; i < n; i += gridDim.x*blockDim.x)
    out[i] = in[i];
}
__global__ void k_zero(float* __restrict__ p, int n) {
  for (int i = blockIdx.x*blockDim.x + threadIdx.x; i < n; i += gridDim.x*blockDim.x)
    p[i] = 0.f;
}
__global__ void k_addf(const float* __restrict__ base, const float* __restrict__ acc,
                       float* __restrict__ out, int n) {
  for (int i = blockIdx.x*blockDim.x + threadIdx.x; i < n; i += gridDim.x*blockDim.x)
    out[i] = base[i] + acc[i];
}
__global__ void k_w2b(const float* s0, const float* s1, const float* s2, const float* s3,
                      const float* s4, const float* s5, const float* s6, const float* s7,
                      const float* s8, const float* s9, const float* s10, const float* s11,
                      short* __restrict__ dst) {
  const float* srcs[12] = {s0,s1,s2,s3,s4,s5,s6,s7,s8,s9,s10,s11};
  const float* src = srcs[blockIdx.y];
  short* d = dst + (size_t)blockIdx.y*6*16384;
  int i = blockIdx.x*1024 + threadIdx.x*4;
  f32x4 v = *(const f32x4*)(src + i);
  d[i+0] = f2b(v[0]); d[i+1] = f2b(v[1]); d[i+2] = f2b(v[2]); d[i+3] = f2b(v[3]);
}

// ============ MFMA GEMM building blocks ============
__device__ __forceinline__ void stage_W(const short* __restrict__ W, short* Ws, int tid) {
  for (int i = tid; i < 128*16; i += 256) {
    int c = i >> 4, g = i & 15;
    bf16x8 w = *(const bf16x8*)(W + c*128 + g*8);
    *(bf16x8*)(&Ws[c*128 + ((g ^ (c & 7))*8)]) = w;
  }
}
__device__ __forceinline__ void stage_A_ln(const float* __restrict__ F, int row0,
                                           const float* __restrict__ g,
                                           const float* __restrict__ b,
                                           short* As, int tid) {
  int r = tid >> 2, q4 = tid & 3;
  const float* xrow = F + (size_t)(row0 + r)*128 + q4*32;
  float x[32];
  #pragma unroll
  for (int t = 0; t < 8; t++) { f32x4 v = *(const f32x4*)(xrow + t*4);
    x[t*4+0]=v[0]; x[t*4+1]=v[1]; x[t*4+2]=v[2]; x[t*4+3]=v[3]; }
  float s = 0.f, sq = 0.f;
  #pragma unroll
  for (int t = 0; t < 32; t++) { s += x[t]; sq += x[t]*x[t]; }
  s  += __shfl_xor(s, 1, 64);  s  += __shfl_xor(s, 2, 64);
  sq += __shfl_xor(sq, 1, 64); sq += __shfl_xor(sq, 2, 64);
  float mean = s * (1.f/128.f);
  float var  = sq * (1.f/128.f) - mean*mean;
  float inv  = rsqrtf(var + 1e-5f);
  const float* gp = g + q4*32; const float* bp = b + q4*32;
  #pragma unroll
  for (int ii = 0; ii < 4; ii++) {
    short tmp[8];
    #pragma unroll
    for (int j = 0; j < 8; j++) {
      int t = ii*8 + j;
      tmp[j] = f2b((x[t]-mean)*inv*gp[t] + bp[t]);
    }
    bf16x8 pk; __builtin_memcpy(&pk, tmp, 16);
    int gran = (q4*4 + ii) ^ (r & 7);
    *(bf16x8*)(&As[r*128 + gran*8]) = pk;
  }
}
__device__ __forceinline__ void stage_A_bf(const short* __restrict__ A, int row0,
                                           short* As, int tid) {
  for (int i = tid; i < 64*16; i += 256) {
    int r = i >> 4, g = i & 15;
    bf16x8 v = *(const bf16x8*)(A + (size_t)(row0 + r)*128 + g*8);
    *(bf16x8*)(&As[r*128 + ((g ^ (r & 7))*8)]) = v;
  }
}
__device__ __forceinline__ void mfma_core(const short* As, const short* Ws,
                                          int wave, int lane, f32x4 acc[8]) {
  bf16x8 af[4];
  int rl = wave*16 + (lane & 15);
  #pragma unroll
  for (int kc = 0; kc < 4; kc++) {
    int g = (kc*4 + (lane >> 4)) ^ (rl & 7);
    af[kc] = *(const bf16x8*)(&As[rl*128 + g*8]);
  }
  #pragma unroll
  for (int ct = 0; ct < 8; ct++) {
    int c = ct*16 + (lane & 15);
    #pragma unroll
    for (int kc = 0; kc < 4; kc++) {
      int g = (kc*4 + (lane >> 4)) ^ (c & 7);
      bf16x8 bf = *(const bf16x8*)(&Ws[c*128 + g*8]);
      acc[ct] = mfma16(af[kc], bf, acc[ct]);
    }
  }
}

// ---- fused LN + q/k/v projections (one block = 64 rows, all 3 outputs) ----
__global__ __launch_bounds__(256) void k_qkv3(const float* __restrict__ F,
                                              const short* __restrict__ Wq,
                                              const short* __restrict__ Wk,
                                              const short* __restrict__ Wv,
                                              const float* __restrict__ g,
                                              const float* __restrict__ b,
                                              short* __restrict__ Qo,
                                              short* __restrict__ Ko,
                                              short* __restrict__ Vo,
                                              int phi_mask, float qscale) {
  __shared__ short As[64*128];
  __shared__ short Ws[128*128];
  int tid = threadIdx.x;
  int row0 = blockIdx.x * 64;
  stage_A_ln(F, row0, g, b, As, tid);
  int wave = tid >> 6, lane = tid & 63;
  int rbase = row0 + wave*16 + (lane >> 4)*4;
  int cl = lane & 15;
  const short* Wp[3] = {Wq, Wk, Wv};
  short* Op[3] = {Qo, Ko, Vo};
  for (int y = 0; y < 3; y++) {
    __syncthreads();                  // As ready / prev mfma done with Ws
    stage_W(Wp[y], Ws, tid);
    __syncthreads();
    f32x4 acc[8] = {};
    mfma_core(As, Ws, wave, lane, acc);
    bool phi = (phi_mask >> y) & 1;
    float sc = (y == 0) ? qscale : 1.0f;
    short* OUT = Op[y];
    #pragma unroll
    for (int ct = 0; ct < 8; ct++)
      #pragma unroll
      for (int reg = 0; reg < 4; reg++) {
        float v = acc[ct][reg] * sc;
        if (phi) v = (v > 0.f) ? v + 1.0f : __expf(v);
        OUT[(size_t)(rbase + reg)*128 + ct*16 + cl] = f2b(v);
      }
  }
}

// ---- fused MLP chain: F += Msg@Wm; mn=LN(F); F += gelu(mn@W1)@W2 ----
__global__ __launch_bounds__(256) void k_mlp(const short* __restrict__ Msg,
                                             const short* __restrict__ Wm,
                                             const short* __restrict__ W1,
                                             const short* __restrict__ W2,
                                             const float* __restrict__ g,
                                             const float* __restrict__ b,
                                             float* __restrict__ F) {
  __shared__ short As[64*128];
  __shared__ short Ws[128*128];
  int tid = threadIdx.x;
  int row0 = blockIdx.x * 64;
  int wave = tid >> 6, lane = tid & 63;
  int lgrp = lane >> 4, cl = lane & 15;
  int rbase = row0 + wave*16 + lgrp*4;

  stage_A_bf(Msg, row0, As, tid);
  stage_W(Wm, Ws, tid);
  __syncthreads();
  f32x4 acc[8] = {};
  mfma_core(As, Ws, wave, lane, acc);
  f32x4 fnew[8];
  #pragma unroll
  for (int ct = 0; ct < 8; ct++)
    #pragma unroll
    for (int reg = 0; reg < 4; reg++)
      fnew[ct][reg] = acc[ct][reg] + F[(size_t)(rbase + reg)*128 + ct*16 + cl];
  // in-register LN: row r = rbase+reg lives in the 16 lanes of this lgrp group
  float mean[4], inv[4];
  #pragma unroll
  for (int reg = 0; reg < 4; reg++) {
    float s = 0.f, sq = 0.f;
    #pragma unroll
    for (int ct = 0; ct < 8; ct++) { float x = fnew[ct][reg]; s += x; sq += x*x; }
    s += __shfl_xor(s, 1, 64); sq += __shfl_xor(sq, 1, 64);
    s += __shfl_xor(s, 2, 64); sq += __shfl_xor(sq, 2, 64);
    s += __shfl_xor(s, 4, 64); sq += __shfl_xor(sq, 4, 64);
    s += __shfl_xor(s, 8, 64); sq += __shfl_xor(sq, 8, 64);
    mean[reg] = s * (1.f/128.f);
    float var = sq * (1.f/128.f) - mean[reg]*mean[reg];
    inv[reg] = rsqrtf(var + 1e-5f);
  }
  __syncthreads();            // everyone done reading As (mfma1) + Ws
  #pragma unroll
  for (int ct = 0; ct < 8; ct++) {
    int c = ct*16 + cl;
    float gg = g[c], bb = b[c];
    #pragma unroll
    for (int reg = 0; reg < 4; reg++) {
      float v = (fnew[ct][reg] - mean[reg]) * inv[reg] * gg + bb;
      int r = wave*16 + lgrp*4 + reg;
      As[r*128 + (((c >> 3) ^ (r & 7))*8) + (c & 7)] = f2b(v);
    }
  }
  stage_W(W1, Ws, tid);
  __syncthreads();
  f32x4 acc2[8] = {};
  mfma_core(As, Ws, wave, lane, acc2);
  __syncthreads();            // done reading As/Ws
  #pragma unroll
  for (int ct = 0; ct < 8; ct++) {
    int c = ct*16 + cl;
    #pragma unroll
    for (int reg = 0; reg < 4; reg++) {
      float v = acc2[ct][reg];
      v = 0.5f*v*(1.0f + erff(v*0.70710678118654752f));
      int r = wave*16 + lgrp*4 + reg;
      As[r*128 + (((c >> 3) ^ (r & 7))*8) + (c & 7)] = f2b(v);
    }
  }
  stage_W(W2, Ws, tid);
  __syncthreads();
  f32x4 acc3[8] = {};
  mfma_core(As, Ws, wave, lane, acc3);
  #pragma unroll
  for (int ct = 0; ct < 8; ct++)
    #pragma unroll
    for (int reg = 0; reg < 4; reg++)
      F[(size_t)(rbase + reg)*128 + ct*16 + cl] = fnew[ct][reg] + acc3[ct][reg];
}

// ---------------- linear attention ----------------
__global__ __launch_bounds__(256) void k_linred(const short* __restrict__ K,
                                                const short* __restrict__ V,
                                                float* __restrict__ kvp) {
  int nh = blockIdx.x;
  int n = nh >> 3, h = nh & 7;
  int chunk = blockIdx.y;
  int r0 = chunk * (SEQ / NCHUNK);
  const short* kb = K + (size_t)n*SEQ*128 + h*16;
  const short* vb = V + (size_t)n*SEQ*128 + h*16;
  __shared__ float ks[16][17], vs[16][17];
  int tid = threadIdx.x;
  int d1 = tid >> 4, d2 = tid & 15;
  float kv = 0.f, ksum = 0.f;
  for (int r = r0; r < r0 + SEQ/NCHUNK; r += 16) {
    __syncthreads();
    int rr = tid >> 4, dd = tid & 15;
    ks[rr][dd] = b2f(kb[(size_t)(r + rr)*128 + dd]);
    vs[rr][dd] = b2f(vb[(size_t)(r + rr)*128 + dd]);
    __syncthreads();
    #pragma unroll
    for (int j = 0; j < 16; j++) {
      float kvl = ks[j][d1];
      kv   += kvl * vs[j][d2];
      ksum += kvl;
    }
  }
  float* dst = kvp + ((size_t)nh*NCHUNK + chunk)*272;
  dst[d1*16 + d2] = kv;
  if (d2 == 0) dst[256 + d1] = ksum;
}

__global__ __launch_bounds__(256) void k_linapply(const short* __restrict__ Q,
                                                  const float* __restrict__ kvp,
                                                  short* __restrict__ MSG) {
  __shared__ float kv[8*272];
  int row0 = blockIdx.x * 16;
  int n = row0 / SEQ;
  int tid = threadIdx.x;
  for (int i = tid; i < 8*272; i += 256) {
    int h = i / 272, j = i % 272;
    const float* src = kvp + ((size_t)(n*8 + h)*NCHUNK)*272 + j;
    float s = 0.f;
    #pragma unroll
    for (int c2 = 0; c2 < NCHUNK; c2++) s += src[(size_t)c2*272];
    kv[i] = s;
  }
  __syncthreads();
  #pragma unroll
  for (int p = 0; p < 8; p++) {
    int idx = tid + p*256;
    int rl = idx >> 7, c = idx & 127;
    int h = c >> 4, d = c & 15;
    int row = row0 + rl;
    const short* qr = Q + (size_t)row*128 + h*16;
    float z = 1e-6f, o = 0.f;
    #pragma unroll
    for (int dd = 0; dd < 16; dd++) {
      float qv = b2f(qr[dd]);
      z += qv * kv[h*272 + 256 + dd];
      o += qv * kv[h*272 + dd*16 + d];
    }
    MSG[(size_t)row*128 + c] = f2b(o / z);
  }
}

// ---------------- full attention: MFMA swapped-operand, 4-way l-split ----------
// grid (96*4, 2); block = (side, n, part); part handles l-tiles [3p, 3p+3).
// Ks swizzled for QK^T; V in subtiled [dblk][s][dl] layout read via
// ds_read_b64_tr_b16 for the PV A-operand.
__global__ __launch_bounds__(256) void k_fullattn(const short* __restrict__ Q,
                                                  const short* __restrict__ K,
                                                  const short* __restrict__ V,
                                                  short* __restrict__ MSG,
                                                  float* __restrict__ AL,
                                                  float* __restrict__ AR) {
  __shared__ short Ks[192*128];        // 48KB swizzled
  __shared__ short Vsub[8*192*16];     // 48KB: [dblk][s][dl]
  __shared__ float rawb[4*12*64*4];    // 48KB: per-wave raw partials
  int side = blockIdx.y;
  int bx = blockIdx.x;
  int n = bx >> 2, part = bx & 3;
  int qbase = side*HALF_R + n*192;
  int kbase = (side^1)*HALF_R + n*192;
  float* rawbase = (side ? AR : AL) + (size_t)n*192*192;
  int tid = threadIdx.x;
  int wave = tid >> 6, lane = tid & 63;
  int lrow = lane & 15, lgrp = lane >> 4;

  #pragma unroll
  for (int i = 0; i < 12; i++) {
    int c = tid + 256*i;               // 3072 chunks of 8 elems
    int s = c >> 4, t8 = c & 15;
    bf16x8 k8 = *(const bf16x8*)(K + (size_t)(kbase + s)*128 + t8*8);
    bf16x4 lo, hi;
    __builtin_memcpy(&lo, &k8, 8);
    __builtin_memcpy(&hi, ((const char*)&k8) + 8, 8);
    *(bf16x4*)(&Ks[s*128 + (((2*t8)   ^ (s & 15))*4)]) = lo;
    *(bf16x4*)(&Ks[s*128 + (((2*t8+1) ^ (s & 15))*4)]) = hi;
    bf16x8 v8 = *(const bf16x8*)(V + (size_t)(kbase + s)*128 + t8*8);
    *(bf16x8*)(&Vsub[(t8 >> 1)*3072 + s*16 + (t8 & 1)*8]) = v8;
  }
  __syncthreads();

  const f32x4 z4 = {0.f, 0.f, 0.f, 0.f};
  for (int li = 0; li < 3; li++) {
    int lt = part*3 + li;
    int l0 = lt*16;
    f32x4 sa[2][12];
    #pragma unroll
    for (int hh = 0; hh < 2; hh++) {
      int h = wave*2 + hh;
      bf16x4 qf = *(const bf16x4*)(Q + (size_t)(qbase + l0 + lrow)*128 + h*16 + lgrp*4);
      int g = h*4 + lgrp;
      #pragma unroll
      for (int st = 0; st < 12; st++) {
        bf16x4 kf = *(const bf16x4*)(&Ks[(st*16 + lrow)*128 + ((g ^ lrow)*4)]);
        sa[hh][st] = mfma16k16(kf, qf, z4);
      }
    }
    #pragma unroll
    for (int hh = 0; hh < 2; hh++) {
      float m = -1e30f;
      #pragma unroll
      for (int st = 0; st < 12; st++)
        m = fmaxf(m, fmaxf(fmaxf(sa[hh][st][0], sa[hh][st][1]),
                           fmaxf(sa[hh][st][2], sa[hh][st][3])));
      m = fmaxf(m, __shfl_xor(m, 16, 64));
      m = fmaxf(m, __shfl_xor(m, 32, 64));
      float sum = 0.f;
      #pragma unroll
      for (int st = 0; st < 12; st++) {
        #pragma unroll
        for (int r = 0; r < 4; r++) {
          float p = __expf(sa[hh][st][r] - m);
          sa[hh][st][r] = p; sum += p;
        }
      }
      sum += __shfl_xor(sum, 16, 64);
      sum += __shfl_xor(sum, 32, 64);
      float inv = 1.f / sum;
      #pragma unroll
      for (int st = 0; st < 12; st++) {
        sa[hh][st][0] *= inv; sa[hh][st][1] *= inv;
        sa[hh][st][2] *= inv; sa[hh][st][3] *= inv;
      }
    }
    // raw partials (this wave's 2 heads)
    #pragma unroll
    for (int st = 0; st < 12; st++) {
      f32x4 rsum = sa[0][st] + sa[1][st];
      *(f32x4*)(&rawb[(((wave*12) + st)*64 + lane)*4]) = rsum;
    }
    // PV via hardware transpose-read of Vsub
    #pragma unroll
    for (int hh = 0; hh < 2; hh++) {
      int h = wave*2 + hh;
      unsigned vaddr = (unsigned)(uintptr_t)(&Vsub[0]) + h*6144 + lane*8;
      bf16x4 vf[12];
      #pragma unroll
      for (int st = 0; st < 12; st++)
        asm volatile("ds_read_b64_tr_b16 %0, %1 offset:0"
                     : "=v"(vf[st]) : "v"(vaddr + st*512));
      asm volatile("s_waitcnt lgkmcnt(0)" ::: "memory");
      __builtin_amdgcn_sched_barrier(0);
      f32x4 o = z4;
      #pragma unroll
      for (int st = 0; st < 12; st++) {
        bf16x4 pf;
        pf[0] = f2b(sa[hh][st][0]); pf[1] = f2b(sa[hh][st][1]);
        pf[2] = f2b(sa[hh][st][2]); pf[3] = f2b(sa[hh][st][3]);
        o = mfma16k16(vf[st], pf, o);
      }
      bf16x4 o4;
      o4[0] = f2b(o[0]); o4[1] = f2b(o[1]); o4[2] = f2b(o[2]); o4[3] = f2b(o[3]);
      *(bf16x4*)(MSG + (size_t)(qbase + l0 + lrow)*128 + h*16 + lgrp*4) = o4;
    }
    __syncthreads();
    #pragma unroll
    for (int i = 0; i < 3; i++) {
      int slot = tid + 256*i;
      int st = slot >> 6, p = slot & 63;
      f32x4 a = *(const f32x4*)(&rawb[((0*12 + st)*64 + p)*4]);
      f32x4 b = *(const f32x4*)(&rawb[((1*12 + st)*64 + p)*4]);
      f32x4 c = *(const f32x4*)(&rawb[((2*12 + st)*64 + p)*4]);
      f32x4 d = *(const f32x4*)(&rawb[((3*12 + st)*64 + p)*4]);
      f32x4 t = (a + b) + (c + d);
      float* gp = rawbase + (size_t)(l0 + (p & 15))*192 + st*16 + ((p >> 4)*4);
      f32x4 cur = *(const f32x4*)gp;
      *(f32x4*)gp = cur + t;
    }
    __syncthreads();
  }
}

// ---------------- launch ----------------
extern "C" void kernel_launch(void* const* d_in, const int* in_sizes, int n_in,
                              void* d_out, int out_size, void* d_ws, size_t ws_size,
                              hipStream_t stream) {
  const float* feat_l = (const float*)d_in[0];
  const float* feat_r = (const float*)d_in[1];
  const float* attn_l = (const float*)d_in[2];
  const float* attn_r = (const float*)d_in[3];
  const float* saw[6] = { (const float*)d_in[4],  (const float*)d_in[6],  (const float*)d_in[8],
                          (const float*)d_in[10], (const float*)d_in[12], (const float*)d_in[14] };
  const float* caw[6] = { (const float*)d_in[5],  (const float*)d_in[7],  (const float*)d_in[9],
                          (const float*)d_in[11], (const float*)d_in[13], (const float*)d_in[15] };
  const float* sa_n1g = (const float*)d_in[16]; const float* ca_n1g = (const float*)d_in[17];
  const float* sa_n1b = (const float*)d_in[18]; const float* ca_n1b = (const float*)d_in[19];
  const float* sa_n2g = (const float*)d_in[20]; const float* ca_n2g = (const float*)d_in[21];
  const float* sa_n2b = (const float*)d_in[22]; const float* ca_n2b = (const float*)d_in[23];

  float* F   = (float*)d_ws;
  float* ALa = F + NE;
  float* ARa = ALa + ATTN_E;
  float* KVp = ARa + ATTN_E;
  short* WB  = (short*)(KVp + 32*NCHUNK*272);
  short* Qb  = WB + 12*6*16384;
  short* Kb  = Qb + NE;
  short* Vb  = Kb + NE;
  short* Mb  = Vb + NE;

  k_w2b<<<dim3(96,12), 256, 0, stream>>>(saw[0],saw[1],saw[2],saw[3],saw[4],saw[5],
                                         caw[0],caw[1],caw[2],caw[3],caw[4],caw[5], WB);
  k_copy<<<1024, 256, 0, stream>>>(feat_l, F, NE/2);
  k_copy<<<1024, 256, 0, stream>>>(feat_r, F + NE/2, NE/2);
  k_zero<<<2048, 256, 0, stream>>>(ALa, 2*ATTN_E);

  for (int i = 0; i < 6; i++) {
    const short* sw[6], *cw[6];
    for (int t = 0; t < 6; t++) { sw[t] = WB + (size_t)(t*6 + i)*16384; cw[t] = WB + (size_t)((6+t)*6 + i)*16384; }
    int vo = i*128;
    // ---- self layer ----
    k_qkv3<<<576, 256, 0, stream>>>(F, sw[0], sw[1], sw[2], sa_n1g+vo, sa_n1b+vo,
                                    Qb, Kb, Vb, 0b011, 1.0f);
    k_linred<<<dim3(32, NCHUNK), 256, 0, stream>>>(Kb, Vb, KVp);
    k_linapply<<<2304, 256, 0, stream>>>(Qb, KVp, Mb);
    k_mlp<<<576, 256, 0, stream>>>(Mb, sw[3], sw[4], sw[5], sa_n2g+vo, sa_n2b+vo, F);
    // ---- cross layer ----
    k_qkv3<<<576, 256, 0, stream>>>(F, cw[0], cw[1], cw[2], ca_n1g+vo, ca_n1b+vo,
                                    Qb, Kb, Vb, 0, 0.25f);
    k_fullattn<<<dim3(384, 2), 256, 0, stream>>>(Qb, Kb, Vb, Mb, ALa, ARa);
    k_mlp<<<576, 256, 0, stream>>>(Mb, cw[3], cw[4], cw[5], ca_n2g+vo, ca_n2b+vo, F);
  }

  float* out = (float*)d_out;
  k_copy<<<2048, 256, 0, stream>>>(F, out, NE);
  k_addf<<<2048, 256, 0, stream>>>(attn_l, ALa, out + NE, ATTN_E);
  k_addf<<<2048, 256, 0, stream>>>(attn_r, ARa, out + NE + ATTN_E, ATTN_E);
}